// Round 1
// baseline (244.076 us; speedup 1.0000x reference)
//
#include <hip/hip_runtime.h>

// Problem constants (from reference): L=4, DIM=17, S=4, B=4, H=256, W=256, BINSIZE=16
#define HH   256
#define WW   256
#define HWPX (HH * WW)          // 65536
#define DD   17
#define D4   (17 * 17 * 17 * 17) // 83521
#define NL   4
#define SS   16                  // S*S

__global__ __launch_bounds__(256) void lut4d_kernel(
    const float* __restrict__ lut,     // (L, D^4, 16)
    const float* __restrict__ weight,  // (B, L, H, W)
    const float* __restrict__ x,       // (B, 1, H, W)
    float* __restrict__ out)           // (B, 1, H*4, W*4)
{
    int p = blockIdx.x * blockDim.x + threadIdx.x;   // pixel id in [0, B*H*W)
    int b  = p >> 16;        // / 65536
    int hw = p & 65535;
    int h  = hw >> 8;
    int w  = hw & 255;

    const float* xb = x + b * HWPX;
    // reflect padding (jnp.pad mode='reflect'): padded index H maps to H-2
    int h1 = (h + 1 < HH) ? (h + 1) : (HH - 2);
    int w1 = (w + 1 < WW) ? (w + 1) : (WW - 2);

    float pix0 = xb[h  * WW + w ];
    float pix1 = xb[h  * WW + w1];
    float pix2 = xb[h1 * WW + w ];
    float pix3 = xb[h1 * WW + w1];

    const float inv = 1.0f / 16.0f;
    float t0 = pix0 * inv, t1 = pix1 * inv, t2 = pix2 * inv, t3 = pix3 * inv;
    float bf0 = floorf(t0), bf1 = floorf(t1), bf2 = floorf(t2), bf3 = floorf(t3);
    float f0 = t0 - bf0, f1 = t1 - bf1, f2 = t2 - bf2, f3 = t3 - bf3;

    int b0 = min(max((int)bf0, 0), DD - 2);
    int b1 = min(max((int)bf1, 0), DD - 2);
    int b2 = min(max((int)bf2, 0), DD - 2);
    int b3 = min(max((int)bf3, 0), DD - 2);

    // Sort (frac, stride) pairs descending by frac; ties keep original index
    // order. Strides are strictly decreasing with index, so tie-break
    // "original index smaller first" == "stride larger first". A sorting
    // network on this strict total order reproduces stable argsort(-frac).
    float s0f = f0, s1f = f1, s2f = f2, s3f = f3;
    int   s0s = 4913, s1s = 289, s2s = 17, s3s = 1;  // D^3, D^2, D, 1

#define CSWAP(fa, sa, fb, sb)                                          \
    do {                                                               \
        bool sw = (fb > fa) || ((fb == fa) && (sb > sa));              \
        float tf = fa; int ts = sa;                                    \
        if (sw) { fa = fb; sa = sb; fb = tf; sb = ts; }                \
    } while (0)

    CSWAP(s0f, s0s, s1f, s1s);
    CSWAP(s2f, s2s, s3f, s3s);
    CSWAP(s0f, s0s, s2f, s2s);
    CSWAP(s1f, s1s, s3f, s3s);
    CSWAP(s1f, s1s, s2f, s2s);
#undef CSWAP

    // Simplex weights
    float wt0 = 1.0f - s0f;
    float wt1 = s0f - s1f;
    float wt2 = s1f - s2f;
    float wt3 = s2f - s3f;
    float wt4 = s3f;

    // Vertex flat indices (incremental along the sorted axis order)
    int flat0 = ((b0 * DD + b1) * DD + b2) * DD + b3;
    int flat1 = flat0 + s0s;
    int flat2 = flat1 + s1s;
    int flat3 = flat2 + s2s;
    int flat4 = flat3 + s3s;
    int flats[5] = { flat0, flat1, flat2, flat3, flat4 };
    float wts[5] = { wt0, wt1, wt2, wt3, wt4 };

    float acc[SS];
#pragma unroll
    for (int i = 0; i < SS; ++i) acc[i] = 0.0f;

    const float* wb = weight + b * (NL * HWPX) + hw;

#pragma unroll
    for (int l = 0; l < NL; ++l) {
        float wl = wb[l * HWPX];
        const float* lbase = lut + (size_t)l * D4 * SS;
#pragma unroll
        for (int k = 0; k < 5; ++k) {
            float c = wl * wts[k];
            const float4* row = (const float4*)(lbase + (size_t)flats[k] * SS);
            float4 r0 = row[0], r1 = row[1], r2 = row[2], r3 = row[3];
            acc[0]  = fmaf(c, r0.x, acc[0]);
            acc[1]  = fmaf(c, r0.y, acc[1]);
            acc[2]  = fmaf(c, r0.z, acc[2]);
            acc[3]  = fmaf(c, r0.w, acc[3]);
            acc[4]  = fmaf(c, r1.x, acc[4]);
            acc[5]  = fmaf(c, r1.y, acc[5]);
            acc[6]  = fmaf(c, r1.z, acc[6]);
            acc[7]  = fmaf(c, r1.w, acc[7]);
            acc[8]  = fmaf(c, r2.x, acc[8]);
            acc[9]  = fmaf(c, r2.y, acc[9]);
            acc[10] = fmaf(c, r2.z, acc[10]);
            acc[11] = fmaf(c, r2.w, acc[11]);
            acc[12] = fmaf(c, r3.x, acc[12]);
            acc[13] = fmaf(c, r3.y, acc[13]);
            acc[14] = fmaf(c, r3.z, acc[14]);
            acc[15] = fmaf(c, r3.w, acc[15]);
        }
    }

    // Store: out[b, 0, h*4 + i, w*4 + j] = acc[i*4+j]
    float* ob = out + (size_t)b * (HH * 4) * (WW * 4) + (size_t)(h * 4) * (WW * 4) + (w * 4);
#pragma unroll
    for (int i = 0; i < 4; ++i) {
        float4 v = make_float4(acc[i * 4 + 0], acc[i * 4 + 1],
                               acc[i * 4 + 2], acc[i * 4 + 3]);
        *((float4*)(ob + (size_t)i * (WW * 4))) = v;
    }
}

extern "C" void kernel_launch(void* const* d_in, const int* in_sizes, int n_in,
                              void* d_out, int out_size, void* d_ws, size_t ws_size,
                              hipStream_t stream) {
    const float* lut    = (const float*)d_in[0];
    // d_in[1] = tri_index (unused by the reference computation)
    const float* weight = (const float*)d_in[2];
    const float* x      = (const float*)d_in[3];
    float* out          = (float*)d_out;

    // B*H*W = 262144 pixels, one thread each
    dim3 grid(1024), block(256);
    hipLaunchKernelGGL(lut4d_kernel, grid, block, 0, stream, lut, weight, x, out);
}

// Round 2
// 209.237 us; speedup vs baseline: 1.1665x; 1.1665x over previous
//
#include <hip/hip_runtime.h>

// Problem constants: L=4, DIM=17, S=4, B=4, H=256, W=256, BINSIZE=16
#define HH   256
#define WW   256
#define HWPX (HH * WW)           // 65536
#define DD   17
#define D4   (17 * 17 * 17 * 17) // 83521
#define NL   4
#define SS   16                  // S*S
#define LUT_FLOATS (NL * D4 * SS)          // 5,345,344 floats
#define LUT_BYTES  ((size_t)LUT_FLOATS * 4) // ~21.4 MB

// ---------------------------------------------------------------------------
// Kernel 1: transpose LUT (L, D4, 16) -> (D4, L, 16) so one vertex's four
// l-rows are a single contiguous 256B block (2 fully-used 128B lines).
// ---------------------------------------------------------------------------
__global__ __launch_bounds__(256) void lut_transpose_kernel(
    const float4* __restrict__ src,  // (L, D4, 4) float4
    float4* __restrict__ dst)        // (D4, L, 4) float4
{
    int t = blockIdx.x * blockDim.x + threadIdx.x;  // float4 index in dst
    if (t >= D4 * NL * 4) return;
    int c4 = t & 3;
    int l  = (t >> 2) & 3;
    int v  = t >> 4;
    // dst[v][l][c4] = src[l][v][c4]; dst index == t (coalesced writes)
    dst[t] = src[(size_t)l * (D4 * 4) + (size_t)v * 4 + c4];
}

// ---------------------------------------------------------------------------
// Kernel 2: main interpolation, gathers from transposed LUT.
// ---------------------------------------------------------------------------
__global__ __launch_bounds__(256) void lut4d_kernel_t(
    const float* __restrict__ lutT,    // (D4, L, 16)
    const float* __restrict__ weight,  // (B, L, H, W)
    const float* __restrict__ x,       // (B, 1, H, W)
    float* __restrict__ out)           // (B, 1, H*4, W*4)
{
    int p = blockIdx.x * blockDim.x + threadIdx.x;
    int b  = p >> 16;
    int hw = p & 65535;
    int h  = hw >> 8;
    int w  = hw & 255;

    const float* xb = x + b * HWPX;
    int h1 = (h + 1 < HH) ? (h + 1) : (HH - 2);   // reflect pad
    int w1 = (w + 1 < WW) ? (w + 1) : (WW - 2);

    float pix0 = xb[h  * WW + w ];
    float pix1 = xb[h  * WW + w1];
    float pix2 = xb[h1 * WW + w ];
    float pix3 = xb[h1 * WW + w1];

    const float inv = 1.0f / 16.0f;
    float t0 = pix0 * inv, t1 = pix1 * inv, t2 = pix2 * inv, t3 = pix3 * inv;
    float bf0 = floorf(t0), bf1 = floorf(t1), bf2 = floorf(t2), bf3 = floorf(t3);
    float f0 = t0 - bf0, f1 = t1 - bf1, f2 = t2 - bf2, f3 = t3 - bf3;

    int b0 = min(max((int)bf0, 0), DD - 2);
    int b1 = min(max((int)bf1, 0), DD - 2);
    int b2 = min(max((int)bf2, 0), DD - 2);
    int b3 = min(max((int)bf3, 0), DD - 2);

    // Stable descending sort of (frac, stride); strides strictly decrease
    // with original index so tie-break by larger stride == stable argsort.
    float s0f = f0, s1f = f1, s2f = f2, s3f = f3;
    int   s0s = 4913, s1s = 289, s2s = 17, s3s = 1;

#define CSWAP(fa, sa, fb, sb)                                          \
    do {                                                               \
        bool sw = (fb > fa) || ((fb == fa) && (sb > sa));              \
        float tf = fa; int ts = sa;                                    \
        if (sw) { fa = fb; sa = sb; fb = tf; sb = ts; }                \
    } while (0)

    CSWAP(s0f, s0s, s1f, s1s);
    CSWAP(s2f, s2s, s3f, s3s);
    CSWAP(s0f, s0s, s2f, s2s);
    CSWAP(s1f, s1s, s3f, s3s);
    CSWAP(s1f, s1s, s2f, s2s);
#undef CSWAP

    float wts[5];
    wts[0] = 1.0f - s0f;
    wts[1] = s0f - s1f;
    wts[2] = s1f - s2f;
    wts[3] = s2f - s3f;
    wts[4] = s3f;

    int flats[5];
    flats[0] = ((b0 * DD + b1) * DD + b2) * DD + b3;
    flats[1] = flats[0] + s0s;
    flats[2] = flats[1] + s1s;
    flats[3] = flats[2] + s2s;
    flats[4] = flats[3] + s3s;

    const float* wb = weight + b * (NL * HWPX) + hw;
    float wl[NL];
#pragma unroll
    for (int l = 0; l < NL; ++l) wl[l] = wb[l * HWPX];

    float acc[SS];
#pragma unroll
    for (int i = 0; i < SS; ++i) acc[i] = 0.0f;

#pragma unroll
    for (int k = 0; k < 5; ++k) {
        // 256B contiguous block: rows for l=0..3 of vertex flats[k]
        const float4* vbase = (const float4*)(lutT + (size_t)flats[k] * (NL * SS));
#pragma unroll
        for (int l = 0; l < NL; ++l) {
            float c = wl[l] * wts[k];
            float4 r0 = vbase[l * 4 + 0];
            float4 r1 = vbase[l * 4 + 1];
            float4 r2 = vbase[l * 4 + 2];
            float4 r3 = vbase[l * 4 + 3];
            acc[0]  = fmaf(c, r0.x, acc[0]);
            acc[1]  = fmaf(c, r0.y, acc[1]);
            acc[2]  = fmaf(c, r0.z, acc[2]);
            acc[3]  = fmaf(c, r0.w, acc[3]);
            acc[4]  = fmaf(c, r1.x, acc[4]);
            acc[5]  = fmaf(c, r1.y, acc[5]);
            acc[6]  = fmaf(c, r1.z, acc[6]);
            acc[7]  = fmaf(c, r1.w, acc[7]);
            acc[8]  = fmaf(c, r2.x, acc[8]);
            acc[9]  = fmaf(c, r2.y, acc[9]);
            acc[10] = fmaf(c, r2.z, acc[10]);
            acc[11] = fmaf(c, r2.w, acc[11]);
            acc[12] = fmaf(c, r3.x, acc[12]);
            acc[13] = fmaf(c, r3.y, acc[13]);
            acc[14] = fmaf(c, r3.z, acc[14]);
            acc[15] = fmaf(c, r3.w, acc[15]);
        }
    }

    float* ob = out + (size_t)b * (HH * 4) * (WW * 4) + (size_t)(h * 4) * (WW * 4) + (w * 4);
#pragma unroll
    for (int i = 0; i < 4; ++i) {
        *((float4*)(ob + (size_t)i * (WW * 4))) =
            make_float4(acc[i * 4 + 0], acc[i * 4 + 1], acc[i * 4 + 2], acc[i * 4 + 3]);
    }
}

// ---------------------------------------------------------------------------
// Fallback (no workspace): original layout, in case ws_size < LUT_BYTES.
// ---------------------------------------------------------------------------
__global__ __launch_bounds__(256) void lut4d_kernel_fallback(
    const float* __restrict__ lut,
    const float* __restrict__ weight,
    const float* __restrict__ x,
    float* __restrict__ out)
{
    int p = blockIdx.x * blockDim.x + threadIdx.x;
    int b  = p >> 16;
    int hw = p & 65535;
    int h  = hw >> 8;
    int w  = hw & 255;

    const float* xb = x + b * HWPX;
    int h1 = (h + 1 < HH) ? (h + 1) : (HH - 2);
    int w1 = (w + 1 < WW) ? (w + 1) : (WW - 2);

    float pix0 = xb[h  * WW + w ];
    float pix1 = xb[h  * WW + w1];
    float pix2 = xb[h1 * WW + w ];
    float pix3 = xb[h1 * WW + w1];

    const float inv = 1.0f / 16.0f;
    float t0 = pix0 * inv, t1 = pix1 * inv, t2 = pix2 * inv, t3 = pix3 * inv;
    float bf0 = floorf(t0), bf1 = floorf(t1), bf2 = floorf(t2), bf3 = floorf(t3);
    float f0 = t0 - bf0, f1 = t1 - bf1, f2 = t2 - bf2, f3 = t3 - bf3;

    int b0 = min(max((int)bf0, 0), DD - 2);
    int b1 = min(max((int)bf1, 0), DD - 2);
    int b2 = min(max((int)bf2, 0), DD - 2);
    int b3 = min(max((int)bf3, 0), DD - 2);

    float s0f = f0, s1f = f1, s2f = f2, s3f = f3;
    int   s0s = 4913, s1s = 289, s2s = 17, s3s = 1;

#define CSWAP(fa, sa, fb, sb)                                          \
    do {                                                               \
        bool sw = (fb > fa) || ((fb == fa) && (sb > sa));              \
        float tf = fa; int ts = sa;                                    \
        if (sw) { fa = fb; sa = sb; fb = tf; sb = ts; }                \
    } while (0)

    CSWAP(s0f, s0s, s1f, s1s);
    CSWAP(s2f, s2s, s3f, s3s);
    CSWAP(s0f, s0s, s2f, s2s);
    CSWAP(s1f, s1s, s3f, s3s);
    CSWAP(s1f, s1s, s2f, s2s);
#undef CSWAP

    float wts[5] = { 1.0f - s0f, s0f - s1f, s1f - s2f, s2f - s3f, s3f };
    int flats[5];
    flats[0] = ((b0 * DD + b1) * DD + b2) * DD + b3;
    flats[1] = flats[0] + s0s;
    flats[2] = flats[1] + s1s;
    flats[3] = flats[2] + s2s;
    flats[4] = flats[3] + s3s;

    float acc[SS];
#pragma unroll
    for (int i = 0; i < SS; ++i) acc[i] = 0.0f;

    const float* wb = weight + b * (NL * HWPX) + hw;

#pragma unroll
    for (int l = 0; l < NL; ++l) {
        float wlv = wb[l * HWPX];
        const float* lbase = lut + (size_t)l * D4 * SS;
#pragma unroll
        for (int k = 0; k < 5; ++k) {
            float c = wlv * wts[k];
            const float4* row = (const float4*)(lbase + (size_t)flats[k] * SS);
#pragma unroll
            for (int q = 0; q < 4; ++q) {
                float4 r = row[q];
                acc[q * 4 + 0] = fmaf(c, r.x, acc[q * 4 + 0]);
                acc[q * 4 + 1] = fmaf(c, r.y, acc[q * 4 + 1]);
                acc[q * 4 + 2] = fmaf(c, r.z, acc[q * 4 + 2]);
                acc[q * 4 + 3] = fmaf(c, r.w, acc[q * 4 + 3]);
            }
        }
    }

    float* ob = out + (size_t)b * (HH * 4) * (WW * 4) + (size_t)(h * 4) * (WW * 4) + (w * 4);
#pragma unroll
    for (int i = 0; i < 4; ++i) {
        *((float4*)(ob + (size_t)i * (WW * 4))) =
            make_float4(acc[i * 4 + 0], acc[i * 4 + 1], acc[i * 4 + 2], acc[i * 4 + 3]);
    }
}

extern "C" void kernel_launch(void* const* d_in, const int* in_sizes, int n_in,
                              void* d_out, int out_size, void* d_ws, size_t ws_size,
                              hipStream_t stream) {
    const float* lut    = (const float*)d_in[0];
    // d_in[1] = tri_index (unused by the reference computation)
    const float* weight = (const float*)d_in[2];
    const float* x      = (const float*)d_in[3];
    float* out          = (float*)d_out;

    dim3 block(256);
    dim3 grid_main(1024);   // 262144 pixels / 256

    if (ws_size >= LUT_BYTES) {
        float* lutT = (float*)d_ws;
        int n_f4 = D4 * NL * 4;                       // 1,336,336 float4s
        dim3 grid_t((n_f4 + 255) / 256);
        hipLaunchKernelGGL(lut_transpose_kernel, grid_t, block, 0, stream,
                           (const float4*)lut, (float4*)lutT);
        hipLaunchKernelGGL(lut4d_kernel_t, grid_main, block, 0, stream,
                           lutT, weight, x, out);
    } else {
        hipLaunchKernelGGL(lut4d_kernel_fallback, grid_main, block, 0, stream,
                           lut, weight, x, out);
    }
}

// Round 3
// 119.907 us; speedup vs baseline: 2.0355x; 1.7450x over previous
//
#include <hip/hip_runtime.h>

// Problem constants: L=4, DIM=17, S=4, B=4, H=256, W=256, BINSIZE=16
#define HH   256
#define WW   256
#define HWPX (HH * WW)           // 65536
#define DD   17
#define D4   (17 * 17 * 17 * 17) // 83521
#define NL   4
#define SS   16                  // S*S
#define LUT_FLOATS (NL * D4 * SS)           // 5,345,344 floats
#define LUT_BYTES  ((size_t)LUT_FLOATS * 4) // ~21.4 MB

// ---------------------------------------------------------------------------
// Kernel 1: transpose LUT (L, D4, 16) -> (D4, L, 16) so one vertex's four
// l-rows are a single contiguous 256B block (2 fully-used 128B lines).
// ---------------------------------------------------------------------------
__global__ __launch_bounds__(256) void lut_transpose_kernel(
    const float4* __restrict__ src,  // (L, D4, 4) float4
    float4* __restrict__ dst)        // (D4, L, 4) float4
{
    int t = blockIdx.x * blockDim.x + threadIdx.x;  // float4 index in dst
    if (t >= D4 * NL * 4) return;
    int c4 = t & 3;
    int l  = (t >> 2) & 3;
    int v  = t >> 4;
    dst[t] = src[(size_t)l * (D4 * 4) + (size_t)v * 4 + c4];
}

// ---------------------------------------------------------------------------
// Kernel 2: main interpolation. 4 lanes per pixel: lane j handles output
// row j of the 4x4 tile (channels 4j..4j+3). Each lane: 20 independent
// 16B gathers, 4 accumulators, one float4 store.
// ---------------------------------------------------------------------------
__global__ __launch_bounds__(256) void lut4d_kernel_q(
    const float* __restrict__ lutT,    // (D4, L, 16)
    const float* __restrict__ weight,  // (B, L, H, W)
    const float* __restrict__ x,       // (B, 1, H, W)
    float* __restrict__ out)           // (B, 1, H*4, W*4)
{
    int tid = blockIdx.x * blockDim.x + threadIdx.x;  // [0, 4*B*H*W)
    int j = tid & 3;          // output row within 4x4 tile
    int p = tid >> 2;         // pixel id
    int b  = p >> 16;
    int hw = p & 65535;
    int h  = hw >> 8;
    int w  = hw & 255;

    const float* xb = x + b * HWPX;
    int h1 = (h + 1 < HH) ? (h + 1) : (HH - 2);   // reflect pad
    int w1 = (w + 1 < WW) ? (w + 1) : (WW - 2);

    float pix0 = xb[h  * WW + w ];
    float pix1 = xb[h  * WW + w1];
    float pix2 = xb[h1 * WW + w ];
    float pix3 = xb[h1 * WW + w1];

    const float inv = 1.0f / 16.0f;
    float t0 = pix0 * inv, t1 = pix1 * inv, t2 = pix2 * inv, t3 = pix3 * inv;
    float bf0 = floorf(t0), bf1 = floorf(t1), bf2 = floorf(t2), bf3 = floorf(t3);
    float f0 = t0 - bf0, f1 = t1 - bf1, f2 = t2 - bf2, f3 = t3 - bf3;

    int b0 = min(max((int)bf0, 0), DD - 2);
    int b1 = min(max((int)bf1, 0), DD - 2);
    int b2 = min(max((int)bf2, 0), DD - 2);
    int b3 = min(max((int)bf3, 0), DD - 2);

    // Stable descending sort of (frac, stride); strides strictly decrease
    // with original index so tie-break by larger stride == stable argsort.
    float s0f = f0, s1f = f1, s2f = f2, s3f = f3;
    int   s0s = 4913, s1s = 289, s2s = 17, s3s = 1;

#define CSWAP(fa, sa, fb, sb)                                          \
    do {                                                               \
        bool sw = (fb > fa) || ((fb == fa) && (sb > sa));              \
        float tf = fa; int ts = sa;                                    \
        if (sw) { fa = fb; sa = sb; fb = tf; sb = ts; }                \
    } while (0)

    CSWAP(s0f, s0s, s1f, s1s);
    CSWAP(s2f, s2s, s3f, s3s);
    CSWAP(s0f, s0s, s2f, s2s);
    CSWAP(s1f, s1s, s3f, s3s);
    CSWAP(s1f, s1s, s2f, s2s);
#undef CSWAP

    float wts[5];
    wts[0] = 1.0f - s0f;
    wts[1] = s0f - s1f;
    wts[2] = s1f - s2f;
    wts[3] = s2f - s3f;
    wts[4] = s3f;

    int flats[5];
    flats[0] = ((b0 * DD + b1) * DD + b2) * DD + b3;
    flats[1] = flats[0] + s0s;
    flats[2] = flats[1] + s1s;
    flats[3] = flats[2] + s2s;
    flats[4] = flats[3] + s3s;

    const float* wb = weight + b * (NL * HWPX) + hw;
    float wl[NL];
#pragma unroll
    for (int l = 0; l < NL; ++l) wl[l] = wb[l * HWPX];

    // Issue all 20 gathers (independent), then FMA.
    float4 r[5][NL];
#pragma unroll
    for (int k = 0; k < 5; ++k) {
        const float4* vbase = (const float4*)(lutT + (size_t)flats[k] * (NL * SS));
#pragma unroll
        for (int l = 0; l < NL; ++l) {
            r[k][l] = vbase[l * 4 + j];   // lanes j=0..3 cover 64B contiguously
        }
    }

    float a0 = 0.f, a1 = 0.f, a2 = 0.f, a3 = 0.f;
#pragma unroll
    for (int k = 0; k < 5; ++k) {
#pragma unroll
        for (int l = 0; l < NL; ++l) {
            float c = wl[l] * wts[k];
            a0 = fmaf(c, r[k][l].x, a0);
            a1 = fmaf(c, r[k][l].y, a1);
            a2 = fmaf(c, r[k][l].z, a2);
            a3 = fmaf(c, r[k][l].w, a3);
        }
    }

    // out[b, 0, h*4 + j, w*4 .. w*4+3]
    float* ob = out + (size_t)b * (HH * 4) * (WW * 4)
                    + (size_t)(h * 4 + j) * (WW * 4) + (w * 4);
    *((float4*)ob) = make_float4(a0, a1, a2, a3);
}

// ---------------------------------------------------------------------------
// Fallback (no workspace): original layout.
// ---------------------------------------------------------------------------
__global__ __launch_bounds__(256) void lut4d_kernel_fallback(
    const float* __restrict__ lut,
    const float* __restrict__ weight,
    const float* __restrict__ x,
    float* __restrict__ out)
{
    int p = blockIdx.x * blockDim.x + threadIdx.x;
    int b  = p >> 16;
    int hw = p & 65535;
    int h  = hw >> 8;
    int w  = hw & 255;

    const float* xb = x + b * HWPX;
    int h1 = (h + 1 < HH) ? (h + 1) : (HH - 2);
    int w1 = (w + 1 < WW) ? (w + 1) : (WW - 2);

    float pix0 = xb[h  * WW + w ];
    float pix1 = xb[h  * WW + w1];
    float pix2 = xb[h1 * WW + w ];
    float pix3 = xb[h1 * WW + w1];

    const float inv = 1.0f / 16.0f;
    float t0 = pix0 * inv, t1 = pix1 * inv, t2 = pix2 * inv, t3 = pix3 * inv;
    float bf0 = floorf(t0), bf1 = floorf(t1), bf2 = floorf(t2), bf3 = floorf(t3);
    float f0 = t0 - bf0, f1 = t1 - bf1, f2 = t2 - bf2, f3 = t3 - bf3;

    int b0 = min(max((int)bf0, 0), DD - 2);
    int b1 = min(max((int)bf1, 0), DD - 2);
    int b2 = min(max((int)bf2, 0), DD - 2);
    int b3 = min(max((int)bf3, 0), DD - 2);

    float s0f = f0, s1f = f1, s2f = f2, s3f = f3;
    int   s0s = 4913, s1s = 289, s2s = 17, s3s = 1;

#define CSWAP(fa, sa, fb, sb)                                          \
    do {                                                               \
        bool sw = (fb > fa) || ((fb == fa) && (sb > sa));              \
        float tf = fa; int ts = sa;                                    \
        if (sw) { fa = fb; sa = sb; fb = tf; sb = ts; }                \
    } while (0)

    CSWAP(s0f, s0s, s1f, s1s);
    CSWAP(s2f, s2s, s3f, s3s);
    CSWAP(s0f, s0s, s2f, s2s);
    CSWAP(s1f, s1s, s3f, s3s);
    CSWAP(s1f, s1s, s2f, s2s);
#undef CSWAP

    float wts[5] = { 1.0f - s0f, s0f - s1f, s1f - s2f, s2f - s3f, s3f };
    int flats[5];
    flats[0] = ((b0 * DD + b1) * DD + b2) * DD + b3;
    flats[1] = flats[0] + s0s;
    flats[2] = flats[1] + s1s;
    flats[3] = flats[2] + s2s;
    flats[4] = flats[3] + s3s;

    float acc[SS];
#pragma unroll
    for (int i = 0; i < SS; ++i) acc[i] = 0.0f;

    const float* wb = weight + b * (NL * HWPX) + hw;

#pragma unroll
    for (int l = 0; l < NL; ++l) {
        float wlv = wb[l * HWPX];
        const float* lbase = lut + (size_t)l * D4 * SS;
#pragma unroll
        for (int k = 0; k < 5; ++k) {
            float c = wlv * wts[k];
            const float4* row = (const float4*)(lbase + (size_t)flats[k] * SS);
#pragma unroll
            for (int q = 0; q < 4; ++q) {
                float4 rr = row[q];
                acc[q * 4 + 0] = fmaf(c, rr.x, acc[q * 4 + 0]);
                acc[q * 4 + 1] = fmaf(c, rr.y, acc[q * 4 + 1]);
                acc[q * 4 + 2] = fmaf(c, rr.z, acc[q * 4 + 2]);
                acc[q * 4 + 3] = fmaf(c, rr.w, acc[q * 4 + 3]);
            }
        }
    }

    float* ob = out + (size_t)b * (HH * 4) * (WW * 4) + (size_t)(h * 4) * (WW * 4) + (w * 4);
#pragma unroll
    for (int i = 0; i < 4; ++i) {
        *((float4*)(ob + (size_t)i * (WW * 4))) =
            make_float4(acc[i * 4 + 0], acc[i * 4 + 1], acc[i * 4 + 2], acc[i * 4 + 3]);
    }
}

extern "C" void kernel_launch(void* const* d_in, const int* in_sizes, int n_in,
                              void* d_out, int out_size, void* d_ws, size_t ws_size,
                              hipStream_t stream) {
    const float* lut    = (const float*)d_in[0];
    // d_in[1] = tri_index (unused by the reference computation)
    const float* weight = (const float*)d_in[2];
    const float* x      = (const float*)d_in[3];
    float* out          = (float*)d_out;

    dim3 block(256);

    if (ws_size >= LUT_BYTES) {
        float* lutT = (float*)d_ws;
        int n_f4 = D4 * NL * 4;                       // 1,336,336 float4s
        dim3 grid_t((n_f4 + 255) / 256);
        hipLaunchKernelGGL(lut_transpose_kernel, grid_t, block, 0, stream,
                           (const float4*)lut, (float4*)lutT);
        dim3 grid_main(4096);   // 4 * 262144 threads / 256
        hipLaunchKernelGGL(lut4d_kernel_q, grid_main, block, 0, stream,
                           lutT, weight, x, out);
    } else {
        dim3 grid_main(1024);
        hipLaunchKernelGGL(lut4d_kernel_fallback, grid_main, block, 0, stream,
                           lut, weight, x, out);
    }
}

// Round 4
// 99.656 us; speedup vs baseline: 2.4492x; 1.2032x over previous
//
#include <hip/hip_runtime.h>
#include <hip/hip_fp16.h>

// Problem constants: L=4, DIM=17, S=4, B=4, H=256, W=256, BINSIZE=16
#define HH   256
#define WW   256
#define HWPX (HH * WW)           // 65536
#define DD   17
#define D4   (17 * 17 * 17 * 17) // 83521
#define NL   4
#define SS   16                  // S*S
#define LUT_FLOATS  (NL * D4 * SS)            // 5,345,344 floats
#define LUT_BYTES_H ((size_t)LUT_FLOATS * 2)  // ~10.7 MB (fp16 transposed copy)

// ---------------------------------------------------------------------------
// Kernel 1: transpose + fp16-convert LUT (L, D4, 16) f32 -> (D4, L, 16) f16.
// One vertex's four l-rows become exactly ONE 128B cache line.
// Thread t handles 4 consecutive halfs (8B) of dst; reads one float4 of src.
// ---------------------------------------------------------------------------
__global__ __launch_bounds__(256) void lut_transpose_h_kernel(
    const float4* __restrict__ src,   // (L, D4, 4) float4
    ushort* __restrict__ dst)         // (D4, L, 16) halfs as ushort
{
    int t = blockIdx.x * blockDim.x + threadIdx.x;  // 4-half chunk index in dst
    if (t >= D4 * NL * 4) return;
    int c4 = t & 3;
    int l  = (t >> 2) & 3;
    int v  = t >> 4;
    float4 r = src[(size_t)l * (D4 * 4) + (size_t)v * 4 + c4];
    ushort4 h;
    h.x = __half_as_ushort(__float2half_rn(r.x));
    h.y = __half_as_ushort(__float2half_rn(r.y));
    h.z = __half_as_ushort(__float2half_rn(r.z));
    h.w = __half_as_ushort(__float2half_rn(r.w));
    *((ushort4*)(dst + (size_t)t * 4)) = h;   // coalesced 8B stores
}

// ---------------------------------------------------------------------------
// Kernel 2: main interpolation. 4 lanes per pixel; lane j = output row j of
// the 4x4 tile. Per (k,l): one 8B gather (4 halfs). Lanes j=0..3 cover each
// 32B l-row contiguously; one vertex = one 128B line.
// ---------------------------------------------------------------------------
__global__ __launch_bounds__(256) void lut4d_kernel_qh(
    const ushort* __restrict__ lutT,   // (D4, L, 16) fp16
    const float* __restrict__ weight,  // (B, L, H, W)
    const float* __restrict__ x,       // (B, 1, H, W)
    float* __restrict__ out)           // (B, 1, H*4, W*4)
{
    int tid = blockIdx.x * blockDim.x + threadIdx.x;  // [0, 4*B*H*W)
    int j = tid & 3;          // output row within 4x4 tile
    int p = tid >> 2;         // pixel id
    int b  = p >> 16;
    int hw = p & 65535;
    int h  = hw >> 8;
    int w  = hw & 255;

    const float* xb = x + b * HWPX;
    int h1 = (h + 1 < HH) ? (h + 1) : (HH - 2);   // reflect pad
    int w1 = (w + 1 < WW) ? (w + 1) : (WW - 2);

    float pix0 = xb[h  * WW + w ];
    float pix1 = xb[h  * WW + w1];
    float pix2 = xb[h1 * WW + w ];
    float pix3 = xb[h1 * WW + w1];

    const float inv = 1.0f / 16.0f;
    float t0 = pix0 * inv, t1 = pix1 * inv, t2 = pix2 * inv, t3 = pix3 * inv;
    float bf0 = floorf(t0), bf1 = floorf(t1), bf2 = floorf(t2), bf3 = floorf(t3);
    float f0 = t0 - bf0, f1 = t1 - bf1, f2 = t2 - bf2, f3 = t3 - bf3;

    int b0 = min(max((int)bf0, 0), DD - 2);
    int b1 = min(max((int)bf1, 0), DD - 2);
    int b2 = min(max((int)bf2, 0), DD - 2);
    int b3 = min(max((int)bf3, 0), DD - 2);

    // Stable descending sort of (frac, stride); strides strictly decrease
    // with original index so tie-break by larger stride == stable argsort.
    float s0f = f0, s1f = f1, s2f = f2, s3f = f3;
    int   s0s = 4913, s1s = 289, s2s = 17, s3s = 1;

#define CSWAP(fa, sa, fb, sb)                                          \
    do {                                                               \
        bool sw = (fb > fa) || ((fb == fa) && (sb > sa));              \
        float tf = fa; int ts = sa;                                    \
        if (sw) { fa = fb; sa = sb; fb = tf; sb = ts; }                \
    } while (0)

    CSWAP(s0f, s0s, s1f, s1s);
    CSWAP(s2f, s2s, s3f, s3s);
    CSWAP(s0f, s0s, s2f, s2s);
    CSWAP(s1f, s1s, s3f, s3s);
    CSWAP(s1f, s1s, s2f, s2s);
#undef CSWAP

    float wts[5];
    wts[0] = 1.0f - s0f;
    wts[1] = s0f - s1f;
    wts[2] = s1f - s2f;
    wts[3] = s2f - s3f;
    wts[4] = s3f;

    int flats[5];
    flats[0] = ((b0 * DD + b1) * DD + b2) * DD + b3;
    flats[1] = flats[0] + s0s;
    flats[2] = flats[1] + s1s;
    flats[3] = flats[2] + s2s;
    flats[4] = flats[3] + s3s;

    const float* wb = weight + b * (NL * HWPX) + hw;
    float wl[NL];
#pragma unroll
    for (int l = 0; l < NL; ++l) wl[l] = wb[l * HWPX];

    // Issue all 20 independent 8B gathers, then convert + FMA.
    uint2 r[5][NL];
#pragma unroll
    for (int k = 0; k < 5; ++k) {
        const ushort* vbase = lutT + (size_t)flats[k] * (NL * SS);
#pragma unroll
        for (int l = 0; l < NL; ++l) {
            r[k][l] = *((const uint2*)(vbase + l * SS + j * 4));
        }
    }

    float a0 = 0.f, a1 = 0.f, a2 = 0.f, a3 = 0.f;
#pragma unroll
    for (int k = 0; k < 5; ++k) {
#pragma unroll
        for (int l = 0; l < NL; ++l) {
            float c = wl[l] * wts[k];
            __half2 h01 = *reinterpret_cast<const __half2*>(&r[k][l].x);
            __half2 h23 = *reinterpret_cast<const __half2*>(&r[k][l].y);
            float2 f01 = __half22float2(h01);
            float2 f23 = __half22float2(h23);
            a0 = fmaf(c, f01.x, a0);
            a1 = fmaf(c, f01.y, a1);
            a2 = fmaf(c, f23.x, a2);
            a3 = fmaf(c, f23.y, a3);
        }
    }

    // out[b, 0, h*4 + j, w*4 .. w*4+3]
    float* ob = out + (size_t)b * (HH * 4) * (WW * 4)
                    + (size_t)(h * 4 + j) * (WW * 4) + (w * 4);
    *((float4*)ob) = make_float4(a0, a1, a2, a3);
}

// ---------------------------------------------------------------------------
// Fallback (no workspace): original layout, fp32.
// ---------------------------------------------------------------------------
__global__ __launch_bounds__(256) void lut4d_kernel_fallback(
    const float* __restrict__ lut,
    const float* __restrict__ weight,
    const float* __restrict__ x,
    float* __restrict__ out)
{
    int p = blockIdx.x * blockDim.x + threadIdx.x;
    int b  = p >> 16;
    int hw = p & 65535;
    int h  = hw >> 8;
    int w  = hw & 255;

    const float* xb = x + b * HWPX;
    int h1 = (h + 1 < HH) ? (h + 1) : (HH - 2);
    int w1 = (w + 1 < WW) ? (w + 1) : (WW - 2);

    float pix0 = xb[h  * WW + w ];
    float pix1 = xb[h  * WW + w1];
    float pix2 = xb[h1 * WW + w ];
    float pix3 = xb[h1 * WW + w1];

    const float inv = 1.0f / 16.0f;
    float t0 = pix0 * inv, t1 = pix1 * inv, t2 = pix2 * inv, t3 = pix3 * inv;
    float bf0 = floorf(t0), bf1 = floorf(t1), bf2 = floorf(t2), bf3 = floorf(t3);
    float f0 = t0 - bf0, f1 = t1 - bf1, f2 = t2 - bf2, f3 = t3 - bf3;

    int b0 = min(max((int)bf0, 0), DD - 2);
    int b1 = min(max((int)bf1, 0), DD - 2);
    int b2 = min(max((int)bf2, 0), DD - 2);
    int b3 = min(max((int)bf3, 0), DD - 2);

    float s0f = f0, s1f = f1, s2f = f2, s3f = f3;
    int   s0s = 4913, s1s = 289, s2s = 17, s3s = 1;

#define CSWAP(fa, sa, fb, sb)                                          \
    do {                                                               \
        bool sw = (fb > fa) || ((fb == fa) && (sb > sa));              \
        float tf = fa; int ts = sa;                                    \
        if (sw) { fa = fb; sa = sb; fb = tf; sb = ts; }                \
    } while (0)

    CSWAP(s0f, s0s, s1f, s1s);
    CSWAP(s2f, s2s, s3f, s3s);
    CSWAP(s0f, s0s, s2f, s2s);
    CSWAP(s1f, s1s, s3f, s3s);
    CSWAP(s1f, s1s, s2f, s2s);
#undef CSWAP

    float wts[5] = { 1.0f - s0f, s0f - s1f, s1f - s2f, s2f - s3f, s3f };
    int flats[5];
    flats[0] = ((b0 * DD + b1) * DD + b2) * DD + b3;
    flats[1] = flats[0] + s0s;
    flats[2] = flats[1] + s1s;
    flats[3] = flats[2] + s2s;
    flats[4] = flats[3] + s3s;

    float acc[SS];
#pragma unroll
    for (int i = 0; i < SS; ++i) acc[i] = 0.0f;

    const float* wb = weight + b * (NL * HWPX) + hw;

#pragma unroll
    for (int l = 0; l < NL; ++l) {
        float wlv = wb[l * HWPX];
        const float* lbase = lut + (size_t)l * D4 * SS;
#pragma unroll
        for (int k = 0; k < 5; ++k) {
            float c = wlv * wts[k];
            const float4* row = (const float4*)(lbase + (size_t)flats[k] * SS);
#pragma unroll
            for (int q = 0; q < 4; ++q) {
                float4 rr = row[q];
                acc[q * 4 + 0] = fmaf(c, rr.x, acc[q * 4 + 0]);
                acc[q * 4 + 1] = fmaf(c, rr.y, acc[q * 4 + 1]);
                acc[q * 4 + 2] = fmaf(c, rr.z, acc[q * 4 + 2]);
                acc[q * 4 + 3] = fmaf(c, rr.w, acc[q * 4 + 3]);
            }
        }
    }

    float* ob = out + (size_t)b * (HH * 4) * (WW * 4) + (size_t)(h * 4) * (WW * 4) + (w * 4);
#pragma unroll
    for (int i = 0; i < 4; ++i) {
        *((float4*)(ob + (size_t)i * (WW * 4))) =
            make_float4(acc[i * 4 + 0], acc[i * 4 + 1], acc[i * 4 + 2], acc[i * 4 + 3]);
    }
}

extern "C" void kernel_launch(void* const* d_in, const int* in_sizes, int n_in,
                              void* d_out, int out_size, void* d_ws, size_t ws_size,
                              hipStream_t stream) {
    const float* lut    = (const float*)d_in[0];
    // d_in[1] = tri_index (unused by the reference computation)
    const float* weight = (const float*)d_in[2];
    const float* x      = (const float*)d_in[3];
    float* out          = (float*)d_out;

    dim3 block(256);

    if (ws_size >= LUT_BYTES_H) {
        ushort* lutT = (ushort*)d_ws;
        int n_chunks = D4 * NL * 4;                   // 1,336,336 4-half chunks
        dim3 grid_t((n_chunks + 255) / 256);
        hipLaunchKernelGGL(lut_transpose_h_kernel, grid_t, block, 0, stream,
                           (const float4*)lut, lutT);
        dim3 grid_main(4096);   // 4 * 262144 threads / 256
        hipLaunchKernelGGL(lut4d_kernel_qh, grid_main, block, 0, stream,
                           lutT, weight, x, out);
    } else {
        dim3 grid_main(1024);
        hipLaunchKernelGGL(lut4d_kernel_fallback, grid_main, block, 0, stream,
                           lut, weight, x, out);
    }
}

// Round 5
// 99.501 us; speedup vs baseline: 2.4530x; 1.0016x over previous
//
#include <hip/hip_runtime.h>
#include <hip/hip_fp16.h>

// Problem constants: L=4, DIM=17, S=4, B=4, H=256, W=256, BINSIZE=16
#define HH   256
#define WW   256
#define HWPX (HH * WW)           // 65536
#define DD   17
#define D4   (17 * 17 * 17 * 17) // 83521
#define NL   4
#define SS   16                  // S*S
#define LUT_FLOATS  (NL * D4 * SS)            // 5,345,344 floats
#define LUT_BYTES_H ((size_t)LUT_FLOATS * 2)  // ~10.7 MB (fp16 transposed copy)

// ---------------------------------------------------------------------------
// Kernel 1: transpose + fp16-convert LUT (L, D4, 16) f32 -> (D4, L, 16) f16.
// One vertex's four l-rows become exactly ONE 128B cache line.
// ---------------------------------------------------------------------------
__global__ __launch_bounds__(256) void lut_transpose_h_kernel(
    const float4* __restrict__ src,   // (L, D4, 4) float4
    ushort* __restrict__ dst)         // (D4, L, 16) halfs as ushort
{
    int t = blockIdx.x * blockDim.x + threadIdx.x;  // 4-half chunk index in dst
    if (t >= D4 * NL * 4) return;
    int c4 = t & 3;
    int l  = (t >> 2) & 3;
    int v  = t >> 4;
    float4 r = src[(size_t)l * (D4 * 4) + (size_t)v * 4 + c4];
    ushort4 h;
    h.x = __half_as_ushort(__float2half_rn(r.x));
    h.y = __half_as_ushort(__float2half_rn(r.y));
    h.z = __half_as_ushort(__float2half_rn(r.z));
    h.w = __half_as_ushort(__float2half_rn(r.w));
    *((ushort4*)(dst + (size_t)t * 4)) = h;   // coalesced 8B stores
}

// ---------------------------------------------------------------------------
// Kernel 2: main interpolation. 8 lanes per pixel; lane j handles channel
// pair (2j, 2j+1). Per (k,l): one 4B gather (2 halfs). Lanes j=0..7 cover
// each 32B l-row contiguously; one vertex = one fully-used 128B line.
// 2M threads -> 2x memory-level parallelism vs the 4-lane version.
// ---------------------------------------------------------------------------
__global__ __launch_bounds__(256) void lut4d_kernel_o(
    const ushort* __restrict__ lutT,   // (D4, L, 16) fp16
    const float* __restrict__ weight,  // (B, L, H, W)
    const float* __restrict__ x,       // (B, 1, H, W)
    float* __restrict__ out)           // (B, 1, H*4, W*4)
{
    int tid = blockIdx.x * blockDim.x + threadIdx.x;  // [0, 8*B*H*W)
    int j = tid & 7;          // channel pair index: channels 2j, 2j+1
    int p = tid >> 3;         // pixel id
    int b  = p >> 16;
    int hw = p & 65535;
    int h  = hw >> 8;
    int w  = hw & 255;

    const float* xb = x + b * HWPX;
    int h1 = (h + 1 < HH) ? (h + 1) : (HH - 2);   // reflect pad
    int w1 = (w + 1 < WW) ? (w + 1) : (WW - 2);

    float pix0 = xb[h  * WW + w ];
    float pix1 = xb[h  * WW + w1];
    float pix2 = xb[h1 * WW + w ];
    float pix3 = xb[h1 * WW + w1];

    const float inv = 1.0f / 16.0f;
    float t0 = pix0 * inv, t1 = pix1 * inv, t2 = pix2 * inv, t3 = pix3 * inv;
    float bf0 = floorf(t0), bf1 = floorf(t1), bf2 = floorf(t2), bf3 = floorf(t3);
    float f0 = t0 - bf0, f1 = t1 - bf1, f2 = t2 - bf2, f3 = t3 - bf3;

    int b0 = min(max((int)bf0, 0), DD - 2);
    int b1 = min(max((int)bf1, 0), DD - 2);
    int b2 = min(max((int)bf2, 0), DD - 2);
    int b3 = min(max((int)bf3, 0), DD - 2);

    // Stable descending sort of (frac, stride); strides strictly decrease
    // with original index so tie-break by larger stride == stable argsort.
    // (Exact ties give the middle vertex weight 0, so order is numerically
    // irrelevant, but keep the tie-break for exact argsort semantics.)
    float s0f = f0, s1f = f1, s2f = f2, s3f = f3;
    int   s0s = 4913, s1s = 289, s2s = 17, s3s = 1;

#define CSWAP(fa, sa, fb, sb)                                          \
    do {                                                               \
        bool sw = (fb > fa) || ((fb == fa) && (sb > sa));              \
        float tf = fa; int ts = sa;                                    \
        if (sw) { fa = fb; sa = sb; fb = tf; sb = ts; }                \
    } while (0)

    CSWAP(s0f, s0s, s1f, s1s);
    CSWAP(s2f, s2s, s3f, s3s);
    CSWAP(s0f, s0s, s2f, s2s);
    CSWAP(s1f, s1s, s3f, s3s);
    CSWAP(s1f, s1s, s2f, s2s);
#undef CSWAP

    float wts[5];
    wts[0] = 1.0f - s0f;
    wts[1] = s0f - s1f;
    wts[2] = s1f - s2f;
    wts[3] = s2f - s3f;
    wts[4] = s3f;

    int flats[5];
    flats[0] = ((b0 * DD + b1) * DD + b2) * DD + b3;
    flats[1] = flats[0] + s0s;
    flats[2] = flats[1] + s1s;
    flats[3] = flats[2] + s2s;
    flats[4] = flats[3] + s3s;

    const float* wb = weight + b * (NL * HWPX) + hw;
    float wl[NL];
#pragma unroll
    for (int l = 0; l < NL; ++l) wl[l] = wb[l * HWPX];

    // Issue all 20 independent 4B gathers, then convert + FMA.
    unsigned int r[5][NL];
#pragma unroll
    for (int k = 0; k < 5; ++k) {
        const ushort* vbase = lutT + (size_t)flats[k] * (NL * SS);
#pragma unroll
        for (int l = 0; l < NL; ++l) {
            r[k][l] = *((const unsigned int*)(vbase + l * SS + j * 2));
        }
    }

    float a0 = 0.f, a1 = 0.f;
#pragma unroll
    for (int k = 0; k < 5; ++k) {
#pragma unroll
        for (int l = 0; l < NL; ++l) {
            float c = wl[l] * wts[k];
            __half2 h01 = *reinterpret_cast<const __half2*>(&r[k][l]);
            float2 f01 = __half22float2(h01);
            a0 = fmaf(c, f01.x, a0);
            a1 = fmaf(c, f01.y, a1);
        }
    }

    // channels (2j, 2j+1) -> out[b, 0, h*4 + (j>>1), w*4 + (j&1)*2 .. +1]
    float* ob = out + (size_t)b * (HH * 4) * (WW * 4)
                    + (size_t)(h * 4 + (j >> 1)) * (WW * 4)
                    + (w * 4) + ((j & 1) * 2);
    *((float2*)ob) = make_float2(a0, a1);
}

// ---------------------------------------------------------------------------
// Fallback (no workspace): original layout, fp32.
// ---------------------------------------------------------------------------
__global__ __launch_bounds__(256) void lut4d_kernel_fallback(
    const float* __restrict__ lut,
    const float* __restrict__ weight,
    const float* __restrict__ x,
    float* __restrict__ out)
{
    int p = blockIdx.x * blockDim.x + threadIdx.x;
    int b  = p >> 16;
    int hw = p & 65535;
    int h  = hw >> 8;
    int w  = hw & 255;

    const float* xb = x + b * HWPX;
    int h1 = (h + 1 < HH) ? (h + 1) : (HH - 2);
    int w1 = (w + 1 < WW) ? (w + 1) : (WW - 2);

    float pix0 = xb[h  * WW + w ];
    float pix1 = xb[h  * WW + w1];
    float pix2 = xb[h1 * WW + w ];
    float pix3 = xb[h1 * WW + w1];

    const float inv = 1.0f / 16.0f;
    float t0 = pix0 * inv, t1 = pix1 * inv, t2 = pix2 * inv, t3 = pix3 * inv;
    float bf0 = floorf(t0), bf1 = floorf(t1), bf2 = floorf(t2), bf3 = floorf(t3);
    float f0 = t0 - bf0, f1 = t1 - bf1, f2 = t2 - bf2, f3 = t3 - bf3;

    int b0 = min(max((int)bf0, 0), DD - 2);
    int b1 = min(max((int)bf1, 0), DD - 2);
    int b2 = min(max((int)bf2, 0), DD - 2);
    int b3 = min(max((int)bf3, 0), DD - 2);

    float s0f = f0, s1f = f1, s2f = f2, s3f = f3;
    int   s0s = 4913, s1s = 289, s2s = 17, s3s = 1;

#define CSWAP(fa, sa, fb, sb)                                          \
    do {                                                               \
        bool sw = (fb > fa) || ((fb == fa) && (sb > sa));              \
        float tf = fa; int ts = sa;                                    \
        if (sw) { fa = fb; sa = sb; fb = tf; sb = ts; }                \
    } while (0)

    CSWAP(s0f, s0s, s1f, s1s);
    CSWAP(s2f, s2s, s3f, s3s);
    CSWAP(s0f, s0s, s2f, s2s);
    CSWAP(s1f, s1s, s3f, s3s);
    CSWAP(s1f, s1s, s2f, s2s);
#undef CSWAP

    float wts[5] = { 1.0f - s0f, s0f - s1f, s1f - s2f, s2f - s3f, s3f };
    int flats[5];
    flats[0] = ((b0 * DD + b1) * DD + b2) * DD + b3;
    flats[1] = flats[0] + s0s;
    flats[2] = flats[1] + s1s;
    flats[3] = flats[2] + s2s;
    flats[4] = flats[3] + s3s;

    float acc[SS];
#pragma unroll
    for (int i = 0; i < SS; ++i) acc[i] = 0.0f;

    const float* wb = weight + b * (NL * HWPX) + hw;

#pragma unroll
    for (int l = 0; l < NL; ++l) {
        float wlv = wb[l * HWPX];
        const float* lbase = lut + (size_t)l * D4 * SS;
#pragma unroll
        for (int k = 0; k < 5; ++k) {
            float c = wlv * wts[k];
            const float4* row = (const float4*)(lbase + (size_t)flats[k] * SS);
#pragma unroll
            for (int q = 0; q < 4; ++q) {
                float4 rr = row[q];
                acc[q * 4 + 0] = fmaf(c, rr.x, acc[q * 4 + 0]);
                acc[q * 4 + 1] = fmaf(c, rr.y, acc[q * 4 + 1]);
                acc[q * 4 + 2] = fmaf(c, rr.z, acc[q * 4 + 2]);
                acc[q * 4 + 3] = fmaf(c, rr.w, acc[q * 4 + 3]);
            }
        }
    }

    float* ob = out + (size_t)b * (HH * 4) * (WW * 4) + (size_t)(h * 4) * (WW * 4) + (w * 4);
#pragma unroll
    for (int i = 0; i < 4; ++i) {
        *((float4*)(ob + (size_t)i * (WW * 4))) =
            make_float4(acc[i * 4 + 0], acc[i * 4 + 1], acc[i * 4 + 2], acc[i * 4 + 3]);
    }
}

extern "C" void kernel_launch(void* const* d_in, const int* in_sizes, int n_in,
                              void* d_out, int out_size, void* d_ws, size_t ws_size,
                              hipStream_t stream) {
    const float* lut    = (const float*)d_in[0];
    // d_in[1] = tri_index (unused by the reference computation)
    const float* weight = (const float*)d_in[2];
    const float* x      = (const float*)d_in[3];
    float* out          = (float*)d_out;

    dim3 block(256);

    if (ws_size >= LUT_BYTES_H) {
        ushort* lutT = (ushort*)d_ws;
        int n_chunks = D4 * NL * 4;                   // 1,336,336 4-half chunks
        dim3 grid_t((n_chunks + 255) / 256);
        hipLaunchKernelGGL(lut_transpose_h_kernel, grid_t, block, 0, stream,
                           (const float4*)lut, lutT);
        dim3 grid_main(8192);   // 8 * 262144 threads / 256
        hipLaunchKernelGGL(lut4d_kernel_o, grid_main, block, 0, stream,
                           lutT, weight, x, out);
    } else {
        dim3 grid_main(1024);
        hipLaunchKernelGGL(lut4d_kernel_fallback, grid_main, block, 0, stream,
                           lut, weight, x, out);
    }
}